// Round 1
// baseline (14205.692 us; speedup 1.0000x reference)
//
#include <hip/hip_runtime.h>
#include <stdint.h>

#define NB 64
#define NS 512
#define NI 512
#define NH 512

typedef __attribute__((ext_vector_type(8))) short bf16x8;
typedef __attribute__((ext_vector_type(4))) float f32x4;

__device__ __forceinline__ unsigned short f2bf(float f) {
  unsigned u = __float_as_uint(f);
  return (unsigned short)((u + 0x7fffu + ((u >> 16) & 1u)) >> 16);
}
__device__ __forceinline__ float bf2f(unsigned short h) {
  return __uint_as_float(((unsigned)h) << 16);
}
__device__ __forceinline__ float sigm(float x) { return 1.0f / (1.0f + __expf(-x)); }
__device__ __forceinline__ float tanh_f(float x) {
  float e = __expf(-2.0f * fabsf(x));
  return copysignf((1.0f - e) / (1.0f + e), x);
}

// ws layout (u32 units):
//  [0,256):              flags[4 m-groups][64 producers], monotonic step counters
//  [1024, 1024+65536):   h_ex[2 bufs][64 b][512 j]  (packed bf16 hi | lo<<16)
//  [66560, +8388608):    x_bf16 as u16[64][512][512]
#define FLAGS_OFF 0
#define HEX_OFF 1024
#define XBF_OFF 66560
#define WS_BYTES_NEEDED (XBF_OFF * 4 + (size_t)NB * NS * NI * 2)

__global__ __launch_bounds__(256) void k_xconv(const float* __restrict__ x,
                                               unsigned short* __restrict__ xb) {
  size_t i = ((size_t)blockIdx.x * 256 + threadIdx.x) * 4;
  float4 v = *(const float4*)(x + i);
  ushort4 o;
  o.x = f2bf(v.x); o.y = f2bf(v.y); o.z = f2bf(v.z); o.w = f2bf(v.w);
  *(ushort4*)(xb + i) = o;
}

__global__ __launch_bounds__(256) void k_init(const float* __restrict__ h0,
                                              unsigned int* __restrict__ ws) {
  int idx = blockIdx.x * 256 + threadIdx.x;
  if (idx < NB * NH) {
    float v = h0[idx];
    unsigned short hi = f2bf(v);
    unsigned short lo = f2bf(v - bf2f(hi));
    ws[HEX_OFF + idx] = (unsigned)hi | ((unsigned)lo << 16);
  }
  if (idx < 256) ws[FLAGS_OFF + idx] = 1u;  // h version 0 available
}

// Persistent cooperative LSTM kernel.
// grid 256 WGs x 512 thr. WG: m=bid&3 (16 batches), n=bid>>2 (8 h-cols -> 32 gate rows).
// wave w: n2=w>>2 selects 16-row half, kw=w&3 selects K-quarter (128 of 512).
// Weights live in VGPRs as bf16 hi/lo fragments. h exchanged via ws with
// agent-scope release/acquire flags (placement-independent correctness).
__global__ __launch_bounds__(512, 2) void k_lstm(
    const float* __restrict__ Wih, const float* __restrict__ bih,
    const float* __restrict__ Whh, const float* __restrict__ bhh,
    const float* __restrict__ c0, float* __restrict__ out,
    unsigned int* __restrict__ ws) {
  const int tid = threadIdx.x;
  const int lane = tid & 63;
  const int w = tid >> 6;
  const int n2 = w >> 2;
  const int kw = w & 3;
  const int k0 = kw * 128;
  const int m = blockIdx.x & 3;
  const int n = blockIdx.x >> 2;

  unsigned int* flags = ws + FLAGS_OFF + m * 64;
  unsigned int* hex = ws + HEX_OFF;
  const unsigned short* xb = (const unsigned short*)(ws + XBF_OFF);

  // B-fragment lane mapping: col=lane&15, k=(lane>>4)*8+r
  const int c = lane & 15;
  const int q = lane >> 4;
  const int jj = c & 3;
  const int gate = c >> 2;
  const int wr0 = gate * NH + n * 8 + jj;  // gate row for n2=0 tile
  const int wrow = wr0 + n2 * 4;           // this wave's tile rows

  // ---- stage weight fragments into registers (hi/lo bf16 split) ----
  bf16x8 whh_hi[4], whh_lo[4], wih_hi[4], wih_lo[4];
#pragma unroll
  for (int kc = 0; kc < 4; ++kc) {
    int kb = k0 + kc * 32 + q * 8;
    const float* ph = Whh + (size_t)wrow * NH + kb;
    const float* pi = Wih + (size_t)wrow * NI + kb;
    float4 a0 = *(const float4*)ph, a1 = *(const float4*)(ph + 4);
    float4 b0 = *(const float4*)pi, b1 = *(const float4*)(pi + 4);
    float vh[8] = {a0.x, a0.y, a0.z, a0.w, a1.x, a1.y, a1.z, a1.w};
    float vi[8] = {b0.x, b0.y, b0.z, b0.w, b1.x, b1.y, b1.z, b1.w};
#pragma unroll
    for (int r = 0; r < 8; ++r) {
      unsigned short h16 = f2bf(vh[r]);
      whh_hi[kc][r] = (short)h16;
      whh_lo[kc][r] = (short)f2bf(vh[r] - bf2f(h16));
      unsigned short i16 = f2bf(vi[r]);
      wih_hi[kc][r] = (short)i16;
      wih_lo[kc][r] = (short)f2bf(vi[r] - bf2f(i16));
    }
  }

  const float bias0 = bih[wr0] + bhh[wr0];
  const float bias1 = bih[wr0 + 4] + bhh[wr0 + 4];

  // epilogue state (wave 0): lane = (b = lane&15, j2 = lane>>4); 2 j's per lane
  const int eb = m * 16 + (lane & 15);
  const int j2 = lane >> 4;
  float cst0 = c0[(size_t)eb * NH + n * 8 + j2];
  float cst1 = c0[(size_t)eb * NH + n * 8 + 4 + j2];

  __shared__ float part[7][4][64];  // K/N partials from waves 1..7 (frag layout)
  __shared__ float gl[2][16][17];   // gates [n2][b][col], padded stride 17

  const int arow = m * 16 + (lane & 15);  // A row = batch
  const unsigned short* xbase = xb + (size_t)arow * NS * NI + k0 + q * 8;
  const unsigned int* hbase = hex + (size_t)arow * NH + k0 + q * 8;

  for (int t = 0; t < NS; ++t) {
    // x-path: load + MFMA before the poll (independent of h -> hides latency)
    bf16x8 xf[4];
    const unsigned short* xr = xbase + (size_t)t * NI;
#pragma unroll
    for (int kc = 0; kc < 4; ++kc) xf[kc] = *(const bf16x8*)(xr + kc * 32);

    f32x4 acc = {0.f, 0.f, 0.f, 0.f};
#pragma unroll
    for (int kc = 0; kc < 4; ++kc) {
      acc = __builtin_amdgcn_mfma_f32_16x16x32_bf16(xf[kc], wih_hi[kc], acc, 0, 0, 0);
      acc = __builtin_amdgcn_mfma_f32_16x16x32_bf16(xf[kc], wih_lo[kc], acc, 0, 0, 0);
    }

    // wait for h version t from all 64 producers of this m-group
    unsigned tgt = (unsigned)(t + 1);
    unsigned fl = __hip_atomic_load(flags + lane, __ATOMIC_RELAXED, __HIP_MEMORY_SCOPE_AGENT);
    while (!__all((int)(fl >= tgt))) {
      __builtin_amdgcn_s_sleep(1);
      fl = __hip_atomic_load(flags + lane, __ATOMIC_RELAXED, __HIP_MEMORY_SCOPE_AGENT);
    }
    __builtin_amdgcn_fence(__ATOMIC_ACQUIRE, "agent");

    // h-path: 3-term hi/lo MFMA
    const unsigned int* hr = hbase + (size_t)(t & 1) * (NB * NH);
#pragma unroll
    for (int kc = 0; kc < 4; ++kc) {
      uint4 p0 = *(const uint4*)(hr + kc * 32);
      uint4 p1 = *(const uint4*)(hr + kc * 32 + 4);
      unsigned pw[8] = {p0.x, p0.y, p0.z, p0.w, p1.x, p1.y, p1.z, p1.w};
      bf16x8 hh, hl;
#pragma unroll
      for (int r = 0; r < 8; ++r) {
        hh[r] = (short)(pw[r] & 0xffffu);
        hl[r] = (short)(pw[r] >> 16);
      }
      acc = __builtin_amdgcn_mfma_f32_16x16x32_bf16(hh, whh_hi[kc], acc, 0, 0, 0);
      acc = __builtin_amdgcn_mfma_f32_16x16x32_bf16(hl, whh_hi[kc], acc, 0, 0, 0);
      acc = __builtin_amdgcn_mfma_f32_16x16x32_bf16(hh, whh_lo[kc], acc, 0, 0, 0);
    }

    if (w != 0) {
#pragma unroll
      for (int r = 0; r < 4; ++r) part[w - 1][r][lane] = acc[r];
    }
    __syncthreads();
    // waves 1..7 loop to next poll; own flag (set by wave0 below) gates them,
    // so no WAR hazard on `part`.

    if (w == 0) {
      float g0[4], g1[4];
#pragma unroll
      for (int r = 0; r < 4; ++r) {
        g0[r] = acc[r] + part[0][r][lane] + part[1][r][lane] + part[2][r][lane] + bias0;
        g1[r] = part[3][r][lane] + part[4][r][lane] + part[5][r][lane] + part[6][r][lane] + bias1;
        gl[0][q * 4 + r][c] = g0[r];  // D layout: row=(lane>>4)*4+r, col=lane&15
        gl[1][q * 4 + r][c] = g1[r];
      }
      // same-wave LDS RAW: compiler inserts lgkmcnt waits
      int bb = lane & 15;
      float gi0 = gl[0][bb][j2],      gf0 = gl[0][bb][4 + j2];
      float gg0 = gl[0][bb][8 + j2],  go0 = gl[0][bb][12 + j2];
      float gi1 = gl[1][bb][j2],      gf1 = gl[1][bb][4 + j2];
      float gg1 = gl[1][bb][8 + j2],  go1 = gl[1][bb][12 + j2];
      float cn0 = sigm(gf0) * cst0 + sigm(gi0) * tanh_f(gg0);
      float cn1 = sigm(gf1) * cst1 + sigm(gi1) * tanh_f(gg1);
      cst0 = cn0; cst1 = cn1;
      float hv0 = sigm(go0) * tanh_f(cn0);
      float hv1 = sigm(go1) * tanh_f(cn1);

      int jg0 = n * 8 + j2, jg1 = jg0 + 4;
      out[((size_t)eb * NS + t) * NH + jg0] = hv0;
      out[((size_t)eb * NS + t) * NH + jg1] = hv1;

      unsigned short h0a = f2bf(hv0), l0a = f2bf(hv0 - bf2f(h0a));
      unsigned short h1a = f2bf(hv1), l1a = f2bf(hv1 - bf2f(h1a));
      unsigned int* dst = hex + (size_t)((t + 1) & 1) * (NB * NH) + (size_t)eb * NH;
      __hip_atomic_store(dst + jg0, (unsigned)h0a | ((unsigned)l0a << 16),
                         __ATOMIC_RELAXED, __HIP_MEMORY_SCOPE_AGENT);
      __hip_atomic_store(dst + jg1, (unsigned)h1a | ((unsigned)l1a << 16),
                         __ATOMIC_RELAXED, __HIP_MEMORY_SCOPE_AGENT);

      if (t == NS - 1) {
        size_t hoff = (size_t)NB * NS * NH;
        out[hoff + (size_t)eb * NH + jg0] = hv0;
        out[hoff + (size_t)eb * NH + jg1] = hv1;
        out[hoff + (size_t)NB * NH + (size_t)eb * NH + jg0] = cn0;
        out[hoff + (size_t)NB * NH + (size_t)eb * NH + jg1] = cn1;
      }
      __builtin_amdgcn_fence(__ATOMIC_RELEASE, "agent");
      if (lane == 0)
        __hip_atomic_store(flags + n, (unsigned)(t + 2),
                           __ATOMIC_RELAXED, __HIP_MEMORY_SCOPE_AGENT);
    }
  }
}

extern "C" void kernel_launch(void* const* d_in, const int* in_sizes, int n_in,
                              void* d_out, int out_size, void* d_ws, size_t ws_size,
                              hipStream_t stream) {
  if (ws_size < WS_BYTES_NEEDED) return;  // fail visibly (poisoned d_out) rather than corrupt

  const float* x   = (const float*)d_in[0];
  const float* h0  = (const float*)d_in[1];
  const float* c0  = (const float*)d_in[2];
  const float* Wih = (const float*)d_in[3];
  const float* bih = (const float*)d_in[4];
  const float* Whh = (const float*)d_in[5];
  const float* bhh = (const float*)d_in[6];
  float* out = (float*)d_out;
  unsigned int* ws = (unsigned int*)d_ws;
  unsigned short* xbptr = (unsigned short*)(ws + XBF_OFF);

  k_xconv<<<dim3(16384), dim3(256), 0, stream>>>(x, xbptr);
  k_init<<<dim3(128), dim3(256), 0, stream>>>(h0, ws);

  void* args[] = {(void*)&Wih, (void*)&bih, (void*)&Whh, (void*)&bhh,
                  (void*)&c0,  (void*)&out, (void*)&ws};
  hipLaunchCooperativeKernel((const void*)k_lstm, dim3(256), dim3(512), args, 0, stream);
}

// Round 2
// 4604.626 us; speedup vs baseline: 3.0851x; 3.0851x over previous
//
#include <hip/hip_runtime.h>
#include <stdint.h>

#define NB 64
#define NS 512
#define NI 512
#define NH 512

typedef __attribute__((ext_vector_type(8))) short bf16x8;
typedef __attribute__((ext_vector_type(4))) float f32x4;

__device__ __forceinline__ unsigned short f2bf(float f) {
  unsigned u = __float_as_uint(f);
  return (unsigned short)((u + 0x7fffu + ((u >> 16) & 1u)) >> 16);
}
__device__ __forceinline__ float bf2f(unsigned short h) {
  return __uint_as_float(((unsigned)h) << 16);
}
__device__ __forceinline__ float sigm(float x) { return 1.0f / (1.0f + __expf(-x)); }
__device__ __forceinline__ float tanh_f(float x) {
  float e = __expf(-2.0f * fabsf(x));
  return copysignf((1.0f - e) / (1.0f + e), x);
}

// ws layout (u32 units):
//  [0,256):              flags[4 m-groups][64 producers], monotonic step counters
//  [1024, 1024+65536):   h_ex[2 bufs][64 b][512 j]  (packed bf16 hi | lo<<16)
//  [66560, +8388608):    x_bf16 as u16[64][512][512]
#define FLAGS_OFF 0
#define HEX_OFF 1024
#define XBF_OFF 66560
#define WS_BYTES_NEEDED (XBF_OFF * 4 + (size_t)NB * NS * NI * 2)

__global__ __launch_bounds__(256) void k_xconv(const float* __restrict__ x,
                                               unsigned short* __restrict__ xb) {
  size_t i = ((size_t)blockIdx.x * 256 + threadIdx.x) * 4;
  float4 v = *(const float4*)(x + i);
  ushort4 o;
  o.x = f2bf(v.x); o.y = f2bf(v.y); o.z = f2bf(v.z); o.w = f2bf(v.w);
  *(ushort4*)(xb + i) = o;
}

__global__ __launch_bounds__(256) void k_init(const float* __restrict__ h0,
                                              unsigned int* __restrict__ ws) {
  int idx = blockIdx.x * 256 + threadIdx.x;
  if (idx < NB * NH) {
    float v = h0[idx];
    unsigned short hi = f2bf(v);
    unsigned short lo = f2bf(v - bf2f(hi));
    ws[HEX_OFF + idx] = (unsigned)hi | ((unsigned)lo << 16);
  }
  if (idx < 256) ws[FLAGS_OFF + idx] = 1u;  // h version 0 available
}

// Persistent cooperative LSTM kernel.
// grid 256 WGs x 512 thr. WG: m=bid&3 (16 batches), n=bid>>2 (8 h-cols -> 32 gate rows).
// wave w: n2=w>>2 selects 16-row half, kw=w&3 selects K-quarter (128 of 512).
// NO agent fences: all cross-WG data moves via relaxed agent-scope atomics
// (sc1, coherent at MALL). Producer orders hex-stores -> flag-store with
// s_waitcnt vmcnt(0); consumer ordering = poll control-dependence.
__global__ __launch_bounds__(512, 2) void k_lstm(
    const float* __restrict__ Wih, const float* __restrict__ bih,
    const float* __restrict__ Whh, const float* __restrict__ bhh,
    const float* __restrict__ c0, float* __restrict__ out,
    unsigned int* __restrict__ ws) {
  const int tid = threadIdx.x;
  const int lane = tid & 63;
  const int w = tid >> 6;
  const int n2 = w >> 2;
  const int kw = w & 3;
  const int k0 = kw * 128;
  const int m = blockIdx.x & 3;
  const int n = blockIdx.x >> 2;

  unsigned int* flags = ws + FLAGS_OFF + m * 64;
  unsigned int* hex = ws + HEX_OFF;
  const unsigned short* xb = (const unsigned short*)(ws + XBF_OFF);

  // B-fragment lane mapping: col=lane&15, k=(lane>>4)*8+r
  const int c = lane & 15;
  const int q = lane >> 4;
  const int jj = c & 3;
  const int gate = c >> 2;
  const int wr0 = gate * NH + n * 8 + jj;  // gate row for n2=0 tile
  const int wrow = wr0 + n2 * 4;           // this wave's tile rows

  // ---- stage weight fragments into registers (hi/lo bf16 split) ----
  bf16x8 whh_hi[4], whh_lo[4], wih_hi[4], wih_lo[4];
#pragma unroll
  for (int kc = 0; kc < 4; ++kc) {
    int kb = k0 + kc * 32 + q * 8;
    const float* ph = Whh + (size_t)wrow * NH + kb;
    const float* pi = Wih + (size_t)wrow * NI + kb;
    float4 a0 = *(const float4*)ph, a1 = *(const float4*)(ph + 4);
    float4 b0 = *(const float4*)pi, b1 = *(const float4*)(pi + 4);
    float vh[8] = {a0.x, a0.y, a0.z, a0.w, a1.x, a1.y, a1.z, a1.w};
    float vi[8] = {b0.x, b0.y, b0.z, b0.w, b1.x, b1.y, b1.z, b1.w};
#pragma unroll
    for (int r = 0; r < 8; ++r) {
      unsigned short h16 = f2bf(vh[r]);
      whh_hi[kc][r] = (short)h16;
      whh_lo[kc][r] = (short)f2bf(vh[r] - bf2f(h16));
      unsigned short i16 = f2bf(vi[r]);
      wih_hi[kc][r] = (short)i16;
      wih_lo[kc][r] = (short)f2bf(vi[r] - bf2f(i16));
    }
  }

  const float bias0 = bih[wr0] + bhh[wr0];
  const float bias1 = bih[wr0 + 4] + bhh[wr0 + 4];

  // epilogue state (wave 0): lane = (b = lane&15, j2 = lane>>4); 2 j's per lane
  const int eb = m * 16 + (lane & 15);
  const int j2 = lane >> 4;
  float cst0 = c0[(size_t)eb * NH + n * 8 + j2];
  float cst1 = c0[(size_t)eb * NH + n * 8 + 4 + j2];

  __shared__ float part[7][4][64];  // K/N partials from waves 1..7 (frag layout)
  __shared__ float gl[2][16][17];   // gates [n2][b][col], padded stride 17

  const int arow = m * 16 + (lane & 15);  // A row = batch
  const unsigned short* xbase = xb + (size_t)arow * NS * NI + k0 + q * 8;
  const unsigned long long* hex64 = (const unsigned long long*)hex;
  const size_t hb64 = ((size_t)arow * NH + k0 + q * 8) >> 1;

  // this wave's producers: WGs (m, kw*16 .. kw*16+15); replicate over 4 lane-groups
  const int fidx = kw * 16 + (lane & 15);

  for (int t = 0; t < NS; ++t) {
    // x-path: load + MFMA before the poll (independent of h -> hides latency)
    bf16x8 xf[4];
    const unsigned short* xr = xbase + (size_t)t * NI;
#pragma unroll
    for (int kc = 0; kc < 4; ++kc) xf[kc] = *(const bf16x8*)(xr + kc * 32);

    f32x4 acc = {0.f, 0.f, 0.f, 0.f};
#pragma unroll
    for (int kc = 0; kc < 4; ++kc) {
      acc = __builtin_amdgcn_mfma_f32_16x16x32_bf16(xf[kc], wih_hi[kc], acc, 0, 0, 0);
      acc = __builtin_amdgcn_mfma_f32_16x16x32_bf16(xf[kc], wih_lo[kc], acc, 0, 0, 0);
    }

    // wait for h version t from the 16 producers covering this wave's K-range
    unsigned tgt = (unsigned)(t + 1);
    unsigned fl = __hip_atomic_load(flags + fidx, __ATOMIC_RELAXED, __HIP_MEMORY_SCOPE_AGENT);
    while (!__all((int)(fl >= tgt))) {
      __builtin_amdgcn_s_sleep(1);
      fl = __hip_atomic_load(flags + fidx, __ATOMIC_RELAXED, __HIP_MEMORY_SCOPE_AGENT);
    }
    asm volatile("" ::: "memory");  // keep hex loads below the poll

    // h-path: 3-term hi/lo MFMA; data via agent-scope (sc1) atomic loads
    const unsigned long long* hr = hex64 + (size_t)(t & 1) * (NB * NH / 2) + hb64;
#pragma unroll
    for (int kc = 0; kc < 4; ++kc) {
      unsigned long long d0 = __hip_atomic_load(hr + kc * 16 + 0, __ATOMIC_RELAXED, __HIP_MEMORY_SCOPE_AGENT);
      unsigned long long d1 = __hip_atomic_load(hr + kc * 16 + 1, __ATOMIC_RELAXED, __HIP_MEMORY_SCOPE_AGENT);
      unsigned long long d2 = __hip_atomic_load(hr + kc * 16 + 2, __ATOMIC_RELAXED, __HIP_MEMORY_SCOPE_AGENT);
      unsigned long long d3 = __hip_atomic_load(hr + kc * 16 + 3, __ATOMIC_RELAXED, __HIP_MEMORY_SCOPE_AGENT);
      unsigned pw[8] = {(unsigned)d0, (unsigned)(d0 >> 32), (unsigned)d1, (unsigned)(d1 >> 32),
                        (unsigned)d2, (unsigned)(d2 >> 32), (unsigned)d3, (unsigned)(d3 >> 32)};
      bf16x8 hh, hl;
#pragma unroll
      for (int r = 0; r < 8; ++r) {
        hh[r] = (short)(pw[r] & 0xffffu);
        hl[r] = (short)(pw[r] >> 16);
      }
      acc = __builtin_amdgcn_mfma_f32_16x16x32_bf16(hh, whh_hi[kc], acc, 0, 0, 0);
      acc = __builtin_amdgcn_mfma_f32_16x16x32_bf16(hl, whh_hi[kc], acc, 0, 0, 0);
      acc = __builtin_amdgcn_mfma_f32_16x16x32_bf16(hh, whh_lo[kc], acc, 0, 0, 0);
    }

    if (w != 0) {
#pragma unroll
      for (int r = 0; r < 4; ++r) part[w - 1][r][lane] = acc[r];
    }
    __syncthreads();

    float g0[4], g1[4];
    if (w == 0) {
#pragma unroll
      for (int r = 0; r < 4; ++r) {
        g0[r] = acc[r] + part[0][r][lane] + part[1][r][lane] + part[2][r][lane] + bias0;
        g1[r] = part[3][r][lane] + part[4][r][lane] + part[5][r][lane] + part[6][r][lane] + bias1;
      }
    }
    // second barrier: protects `part` WAR — waves whose 16-producer set does
    // not include this WG could otherwise overwrite part before wave0 reads it
    __syncthreads();

    if (w == 0) {
#pragma unroll
      for (int r = 0; r < 4; ++r) {
        gl[0][q * 4 + r][c] = g0[r];  // D layout: row=(lane>>4)*4+r, col=lane&15
        gl[1][q * 4 + r][c] = g1[r];
      }
      // same-wave LDS RAW: compiler inserts lgkmcnt waits
      int bb = lane & 15;
      float gi0 = gl[0][bb][j2],      gf0 = gl[0][bb][4 + j2];
      float gg0 = gl[0][bb][8 + j2],  go0 = gl[0][bb][12 + j2];
      float gi1 = gl[1][bb][j2],      gf1 = gl[1][bb][4 + j2];
      float gg1 = gl[1][bb][8 + j2],  go1 = gl[1][bb][12 + j2];
      float cn0 = sigm(gf0) * cst0 + sigm(gi0) * tanh_f(gg0);
      float cn1 = sigm(gf1) * cst1 + sigm(gi1) * tanh_f(gg1);
      cst0 = cn0; cst1 = cn1;
      float hv0 = sigm(go0) * tanh_f(cn0);
      float hv1 = sigm(go1) * tanh_f(cn1);

      int jg0 = n * 8 + j2, jg1 = jg0 + 4;

      // publish h first (critical path), then flag, then deferred out stores
      unsigned short h0a = f2bf(hv0), l0a = f2bf(hv0 - bf2f(h0a));
      unsigned short h1a = f2bf(hv1), l1a = f2bf(hv1 - bf2f(h1a));
      unsigned int* dst = hex + (size_t)((t + 1) & 1) * (NB * NH) + (size_t)eb * NH;
      __hip_atomic_store(dst + jg0, (unsigned)h0a | ((unsigned)l0a << 16),
                         __ATOMIC_RELAXED, __HIP_MEMORY_SCOPE_AGENT);
      __hip_atomic_store(dst + jg1, (unsigned)h1a | ((unsigned)l1a << 16),
                         __ATOMIC_RELAXED, __HIP_MEMORY_SCOPE_AGENT);
      asm volatile("s_waitcnt vmcnt(0)" ::: "memory");  // hex stores visible
      if (lane == 0)
        __hip_atomic_store(flags + n, (unsigned)(t + 2),
                           __ATOMIC_RELAXED, __HIP_MEMORY_SCOPE_AGENT);

      out[((size_t)eb * NS + t) * NH + jg0] = hv0;
      out[((size_t)eb * NS + t) * NH + jg1] = hv1;

      if (t == NS - 1) {
        size_t hoff = (size_t)NB * NS * NH;
        out[hoff + (size_t)eb * NH + jg0] = hv0;
        out[hoff + (size_t)eb * NH + jg1] = hv1;
        out[hoff + (size_t)NB * NH + (size_t)eb * NH + jg0] = cn0;
        out[hoff + (size_t)NB * NH + (size_t)eb * NH + jg1] = cn1;
      }
    }
  }
}

extern "C" void kernel_launch(void* const* d_in, const int* in_sizes, int n_in,
                              void* d_out, int out_size, void* d_ws, size_t ws_size,
                              hipStream_t stream) {
  if (ws_size < WS_BYTES_NEEDED) return;  // fail visibly (poisoned d_out) rather than corrupt

  const float* x   = (const float*)d_in[0];
  const float* h0  = (const float*)d_in[1];
  const float* c0  = (const float*)d_in[2];
  const float* Wih = (const float*)d_in[3];
  const float* bih = (const float*)d_in[4];
  const float* Whh = (const float*)d_in[5];
  const float* bhh = (const float*)d_in[6];
  float* out = (float*)d_out;
  unsigned int* ws = (unsigned int*)d_ws;
  unsigned short* xbptr = (unsigned short*)(ws + XBF_OFF);

  k_xconv<<<dim3(16384), dim3(256), 0, stream>>>(x, xbptr);
  k_init<<<dim3(128), dim3(256), 0, stream>>>(h0, ws);

  void* args[] = {(void*)&Wih, (void*)&bih, (void*)&Whh, (void*)&bhh,
                  (void*)&c0,  (void*)&out, (void*)&ws};
  hipLaunchCooperativeKernel((const void*)k_lstm, dim3(256), dim3(512), args, 0, stream);
}

// Round 3
// 2565.055 us; speedup vs baseline: 5.5382x; 1.7951x over previous
//
#include <hip/hip_runtime.h>
#include <stdint.h>

#define NB 64
#define NS 512
#define NI 512
#define NH 512

typedef __attribute__((ext_vector_type(8))) short bf16x8;
typedef __attribute__((ext_vector_type(4))) float f32x4;

__device__ __forceinline__ unsigned short f2bf(float f) {
  unsigned u = __float_as_uint(f);
  return (unsigned short)((u + 0x7fffu + ((u >> 16) & 1u)) >> 16);
}
__device__ __forceinline__ float bf2f(unsigned short h) {
  return __uint_as_float(((unsigned)h) << 16);
}
__device__ __forceinline__ float sigm(float x) { return 1.0f / (1.0f + __expf(-x)); }
__device__ __forceinline__ float tanh_f(float x) {
  float e = __expf(-2.0f * fabsf(x));
  return copysignf((1.0f - e) / (1.0f + e), x);
}

// ws layout (u32 units):
//  [0,256):              flags[4 m-groups][64 producers], monotonic step counters
//  [1024, 1024+65536):   h_ex[2 bufs][64 b][512 j]  (packed bf16 hi | lo<<16)
//  [66560, +8388608):    x_bf16 as u16[64][512][512]
#define FLAGS_OFF 0
#define HEX_OFF 1024
#define XBF_OFF 66560
#define WS_BYTES_NEEDED (XBF_OFF * 4 + (size_t)NB * NS * NI * 2)

__global__ __launch_bounds__(256) void k_xconv(const float* __restrict__ x,
                                               unsigned short* __restrict__ xb) {
  size_t i = ((size_t)blockIdx.x * 256 + threadIdx.x) * 4;
  float4 v = *(const float4*)(x + i);
  ushort4 o;
  o.x = f2bf(v.x); o.y = f2bf(v.y); o.z = f2bf(v.z); o.w = f2bf(v.w);
  *(ushort4*)(xb + i) = o;
}

__global__ __launch_bounds__(256) void k_init(const float* __restrict__ h0,
                                              unsigned int* __restrict__ ws) {
  int idx = blockIdx.x * 256 + threadIdx.x;
  if (idx < NB * NH) {
    float v = h0[idx];
    unsigned short hi = f2bf(v);
    unsigned short lo = f2bf(v - bf2f(hi));
    ws[HEX_OFF + idx] = (unsigned)hi | ((unsigned)lo << 16);
  }
  if (idx < 256) ws[FLAGS_OFF + idx] = 1u;  // h version 0 available
}

// Persistent cooperative LSTM kernel.
// grid 256 WGs x 512 thr. WG: m=bid&3 (16 batches), n=bid>>2 (8 h-cols -> 32 gate rows).
// wave w: n2=w>>2 selects 16-row half, kw=w&3 selects K-quarter (128 of 512).
// h exchange: producers sc1-write-through to MALL; per WG, wave 7 polls the
// m-group's 64 flags, does ONE acquire fence (buffer_inv, no writeback), then
// stages the 16x512 h-block into LDS via coalesced cached global_load_lds
// (L2-deduped across the 32 same-m WGs of each XCD). All waves read MFMA
// fragments from LDS.
__global__ __launch_bounds__(512, 2) void k_lstm(
    const float* __restrict__ Wih, const float* __restrict__ bih,
    const float* __restrict__ Whh, const float* __restrict__ bhh,
    const float* __restrict__ c0, float* __restrict__ out,
    unsigned int* __restrict__ ws) {
  const int tid = threadIdx.x;
  const int lane = tid & 63;
  const int w = tid >> 6;
  const int n2 = w >> 2;
  const int kw = w & 3;
  const int k0 = kw * 128;
  const int m = blockIdx.x & 3;
  const int n = blockIdx.x >> 2;

  unsigned int* flags = ws + FLAGS_OFF + m * 64;
  unsigned int* hex = ws + HEX_OFF;
  const unsigned short* xb = (const unsigned short*)(ws + XBF_OFF);

  // B-fragment lane mapping: col=lane&15, k=(lane>>4)*8+r
  const int c = lane & 15;
  const int q = lane >> 4;
  const int jj = c & 3;
  const int gate = c >> 2;
  const int wr0 = gate * NH + n * 8 + jj;  // gate row for n2=0 tile
  const int wrow = wr0 + n2 * 4;           // this wave's tile rows

  // ---- stage weight fragments into registers (hi/lo bf16 split) ----
  bf16x8 whh_hi[4], whh_lo[4], wih_hi[4], wih_lo[4];
#pragma unroll
  for (int kc = 0; kc < 4; ++kc) {
    int kb = k0 + kc * 32 + q * 8;
    const float* ph = Whh + (size_t)wrow * NH + kb;
    const float* pi = Wih + (size_t)wrow * NI + kb;
    float4 a0 = *(const float4*)ph, a1 = *(const float4*)(ph + 4);
    float4 b0 = *(const float4*)pi, b1 = *(const float4*)(pi + 4);
    float vh[8] = {a0.x, a0.y, a0.z, a0.w, a1.x, a1.y, a1.z, a1.w};
    float vi[8] = {b0.x, b0.y, b0.z, b0.w, b1.x, b1.y, b1.z, b1.w};
#pragma unroll
    for (int r = 0; r < 8; ++r) {
      unsigned short h16 = f2bf(vh[r]);
      whh_hi[kc][r] = (short)h16;
      whh_lo[kc][r] = (short)f2bf(vh[r] - bf2f(h16));
      unsigned short i16 = f2bf(vi[r]);
      wih_hi[kc][r] = (short)i16;
      wih_lo[kc][r] = (short)f2bf(vi[r] - bf2f(i16));
    }
  }

  const float bias0 = bih[wr0] + bhh[wr0];
  const float bias1 = bih[wr0 + 4] + bhh[wr0 + 4];

  // epilogue state (wave 0): lane = (b = lane&15, j2 = lane>>4); 2 j's per lane
  const int eb = m * 16 + (lane & 15);
  const int j2 = lane >> 4;
  float cst0 = c0[(size_t)eb * NH + n * 8 + j2];
  float cst1 = c0[(size_t)eb * NH + n * 8 + 4 + j2];

  // LDS: staged h block (row stride 516 u32 -> b128 start banks uniform), partials, gates
  __shared__ unsigned Lhex[16][516];
  __shared__ float part[7][4][64];
  __shared__ float gl[2][16][17];

  const int arow = m * 16 + (lane & 15);  // A row = batch (global)
  const unsigned short* xbase = xb + (size_t)arow * NS * NI + k0 + q * 8;

  for (int t = 0; t < NS; ++t) {
    // x-path: load + MFMA (independent of h; overlaps loader's poll/stage)
    bf16x8 xf[4];
    const unsigned short* xr = xbase + (size_t)t * NI;
#pragma unroll
    for (int kc = 0; kc < 4; ++kc) xf[kc] = *(const bf16x8*)(xr + kc * 32);

    f32x4 acc = {0.f, 0.f, 0.f, 0.f};
#pragma unroll
    for (int kc = 0; kc < 4; ++kc) {
      acc = __builtin_amdgcn_mfma_f32_16x16x32_bf16(xf[kc], wih_hi[kc], acc, 0, 0, 0);
      acc = __builtin_amdgcn_mfma_f32_16x16x32_bf16(xf[kc], wih_lo[kc], acc, 0, 0, 0);
    }

    if (w == 7) {
      // loader wave: wait for h version t from all 64 producers of this m-group
      unsigned tgt = (unsigned)(t + 1);
      unsigned fl = __hip_atomic_load(flags + lane, __ATOMIC_RELAXED, __HIP_MEMORY_SCOPE_AGENT);
      while (!__all((int)(fl >= tgt))) {
        __builtin_amdgcn_s_sleep(1);
        fl = __hip_atomic_load(flags + lane, __ATOMIC_RELAXED, __HIP_MEMORY_SCOPE_AGENT);
      }
      // acquire: invalidate stale clean L1/L2 lines; subsequent cached loads hit MALL-fresh data
      __builtin_amdgcn_fence(__ATOMIC_ACQUIRE, "agent");
      // stage 16 batches x 512 cols (32 KB) into LDS, coalesced, via L2
      const unsigned* src = hex + (size_t)(t & 1) * (NB * NH) + (size_t)m * 16 * NH;
#pragma unroll
      for (int bl = 0; bl < 16; ++bl) {
        const unsigned* g0 = src + bl * NH + lane * 4;
        __builtin_amdgcn_global_load_lds(
            (const __attribute__((address_space(1))) unsigned*)g0,
            (__attribute__((address_space(3))) unsigned*)&Lhex[bl][0], 16, 0, 0);
        __builtin_amdgcn_global_load_lds(
            (const __attribute__((address_space(1))) unsigned*)(g0 + 256),
            (__attribute__((address_space(3))) unsigned*)&Lhex[bl][256], 16, 0, 0);
      }
    }
    __syncthreads();  // S1: staging visible (barrier drains loader's vmcnt)

    // h-path: fragments from LDS; 3-term hi/lo MFMA
    const unsigned* Lrow = &Lhex[lane & 15][k0 + q * 8];
#pragma unroll
    for (int kc = 0; kc < 4; ++kc) {
      uint4 p0 = *(const uint4*)(Lrow + kc * 32);
      uint4 p1 = *(const uint4*)(Lrow + kc * 32 + 4);
      unsigned pw[8] = {p0.x, p0.y, p0.z, p0.w, p1.x, p1.y, p1.z, p1.w};
      bf16x8 hh, hl;
#pragma unroll
      for (int r = 0; r < 8; ++r) {
        hh[r] = (short)(pw[r] & 0xffffu);
        hl[r] = (short)(pw[r] >> 16);
      }
      acc = __builtin_amdgcn_mfma_f32_16x16x32_bf16(hh, whh_hi[kc], acc, 0, 0, 0);
      acc = __builtin_amdgcn_mfma_f32_16x16x32_bf16(hl, whh_hi[kc], acc, 0, 0, 0);
      acc = __builtin_amdgcn_mfma_f32_16x16x32_bf16(hh, whh_lo[kc], acc, 0, 0, 0);
    }

    if (w != 0) {
#pragma unroll
      for (int r = 0; r < 4; ++r) part[w - 1][r][lane] = acc[r];
    }
    __syncthreads();  // S2
    // WAR safety: wave0 reads part right after S2(t); other waves' next part
    // write happens only after S1(t+1), which wave0 must also reach first.

    if (w == 0) {
      float g0[4], g1[4];
#pragma unroll
      for (int r = 0; r < 4; ++r) {
        g0[r] = acc[r] + part[0][r][lane] + part[1][r][lane] + part[2][r][lane] + bias0;
        g1[r] = part[3][r][lane] + part[4][r][lane] + part[5][r][lane] + part[6][r][lane] + bias1;
        gl[0][q * 4 + r][c] = g0[r];  // D layout: row=(lane>>4)*4+r, col=lane&15
        gl[1][q * 4 + r][c] = g1[r];
      }
      // same-wave LDS RAW: compiler inserts lgkmcnt waits
      int bb = lane & 15;
      float gi0 = gl[0][bb][j2],      gf0 = gl[0][bb][4 + j2];
      float gg0 = gl[0][bb][8 + j2],  go0 = gl[0][bb][12 + j2];
      float gi1 = gl[1][bb][j2],      gf1 = gl[1][bb][4 + j2];
      float gg1 = gl[1][bb][8 + j2],  go1 = gl[1][bb][12 + j2];
      float cn0 = sigm(gf0) * cst0 + sigm(gi0) * tanh_f(gg0);
      float cn1 = sigm(gf1) * cst1 + sigm(gi1) * tanh_f(gg1);
      cst0 = cn0; cst1 = cn1;
      float hv0 = sigm(go0) * tanh_f(cn0);
      float hv1 = sigm(go1) * tanh_f(cn1);

      int jg0 = n * 8 + j2, jg1 = jg0 + 4;

      // publish h (critical path): sc1 write-through to MALL, ack, then flag
      unsigned short h0a = f2bf(hv0), l0a = f2bf(hv0 - bf2f(h0a));
      unsigned short h1a = f2bf(hv1), l1a = f2bf(hv1 - bf2f(h1a));
      unsigned int* dst = hex + (size_t)((t + 1) & 1) * (NB * NH) + (size_t)eb * NH;
      __hip_atomic_store(dst + jg0, (unsigned)h0a | ((unsigned)l0a << 16),
                         __ATOMIC_RELAXED, __HIP_MEMORY_SCOPE_AGENT);
      __hip_atomic_store(dst + jg1, (unsigned)h1a | ((unsigned)l1a << 16),
                         __ATOMIC_RELAXED, __HIP_MEMORY_SCOPE_AGENT);
      asm volatile("s_waitcnt vmcnt(0)" ::: "memory");  // hex stores at MALL
      if (lane == 0)
        __hip_atomic_store(flags + n, (unsigned)(t + 2),
                           __ATOMIC_RELAXED, __HIP_MEMORY_SCOPE_AGENT);

      // deferred, non-critical stores (normal cached path)
      out[((size_t)eb * NS + t) * NH + jg0] = hv0;
      out[((size_t)eb * NS + t) * NH + jg1] = hv1;

      if (t == NS - 1) {
        size_t hoff = (size_t)NB * NS * NH;
        out[hoff + (size_t)eb * NH + jg0] = hv0;
        out[hoff + (size_t)eb * NH + jg1] = hv1;
        out[hoff + (size_t)NB * NH + (size_t)eb * NH + jg0] = cn0;
        out[hoff + (size_t)NB * NH + (size_t)eb * NH + jg1] = cn1;
      }
    }
  }
}

extern "C" void kernel_launch(void* const* d_in, const int* in_sizes, int n_in,
                              void* d_out, int out_size, void* d_ws, size_t ws_size,
                              hipStream_t stream) {
  if (ws_size < WS_BYTES_NEEDED) return;  // fail visibly (poisoned d_out) rather than corrupt

  const float* x   = (const float*)d_in[0];
  const float* h0  = (const float*)d_in[1];
  const float* c0  = (const float*)d_in[2];
  const float* Wih = (const float*)d_in[3];
  const float* bih = (const float*)d_in[4];
  const float* Whh = (const float*)d_in[5];
  const float* bhh = (const float*)d_in[6];
  float* out = (float*)d_out;
  unsigned int* ws = (unsigned int*)d_ws;
  unsigned short* xbptr = (unsigned short*)(ws + XBF_OFF);

  k_xconv<<<dim3(16384), dim3(256), 0, stream>>>(x, xbptr);
  k_init<<<dim3(128), dim3(256), 0, stream>>>(h0, ws);

  void* args[] = {(void*)&Wih, (void*)&bih, (void*)&Whh, (void*)&bhh,
                  (void*)&c0,  (void*)&out, (void*)&ws};
  hipLaunchCooperativeKernel((const void*)k_lstm, dim3(256), dim3(512), args, 0, stream);
}